// Round 16
// baseline (594.662 us; speedup 1.0000x reference)
//
#include <hip/hip_runtime.h>

typedef unsigned short u16;
typedef unsigned int u32;
typedef __bf16 bf16x8 __attribute__((ext_vector_type(8)));
typedef float f32x4 __attribute__((ext_vector_type(4)));
typedef u16 u16x8 __attribute__((ext_vector_type(8)));

#define NTOK 8192
#define CDIM 1024
#define NEXP 8
#define FEDIM 1024
#define FSDIM 4096

#define GLD16(gp, lp) __builtin_amdgcn_global_load_lds( \
    (const __attribute__((address_space(1))) void*)(gp), \
    (__attribute__((address_space(3))) void*)(lp), 16, 0, 0)

__device__ __forceinline__ u16 f2bf(float f) {
  u32 u = __float_as_uint(f);
  u += 0x7FFFu + ((u >> 16) & 1u);   // RNE
  return (u16)(u >> 16);
}

// ---- 64x32 transpose tile body: src f32[R][C] -> dst bf16[C][R] ------------
__device__ __forceinline__ void transpose64_body(
    const float* __restrict__ src, u16* __restrict__ dst,
    int R, int C, int bx, int by)
{
  __shared__ float tile[64][33];
  int c0 = bx * 32, r0 = by * 64;
  int tx = threadIdx.x & 31, ty = threadIdx.x >> 5;   // ty 0..7
#pragma unroll
  for (int p = 0; p < 8; p++) {
    int r = ty + p * 8;
    tile[r][tx] = src[(size_t)(r0 + r) * C + c0 + tx];
  }
  __syncthreads();
#pragma unroll
  for (int p = 0; p < 4; p++) {
    int cc = ty + p * 8;
    u32 v = (u32)f2bf(tile[2 * tx][cc]) | ((u32)f2bf(tile[2 * tx + 1][cc]) << 16);
    *(u32*)&dst[(size_t)(c0 + cc) * R + r0 + 2 * tx] = v;
  }
}

// ---------------- prep: gate FIRST, then all transposes, ONE launch ----------
// flat bid roles: [0,256) gate; [256,12544) expert-trio transpose
// (24 x 1024^2); [12544,16640) shared W1/W2 pair; [16640,18688) swp.
__global__ __launch_bounds__(256) void prep_kernel(
    const float* __restrict__ x, const float* __restrict__ gw,
    const float* __restrict__ ew1, const float* __restrict__ ew2,
    const float* __restrict__ ewp, const float* __restrict__ sw1,
    const float* __restrict__ sw2, const float* __restrict__ swp,
    float* __restrict__ scores, u16* __restrict__ xb, int* __restrict__ cnt,
    int* __restrict__ tok, float* __restrict__ wgt,
    u16* __restrict__ eall, u16* __restrict__ s12t, u16* __restrict__ swpt)
{
  int bid = blockIdx.x;
  if (bid >= 256) {
    int tb = bid - 256;
    if (tb < 12288) {
      int z = tb >> 9, r = tb & 511;                // z 0..23
      const float* src = (z < 8) ? ew1 : ((z < 16) ? ew2 : ewp);
      transpose64_body(src + (size_t)(z & 7) * CDIM * FEDIM,
                       eall + (size_t)z * CDIM * FEDIM,
                       CDIM, FEDIM, r & 31, r >> 5);
    } else if (tb < 16384) {
      int i2 = tb - 12288;
      int z = i2 >> 11, r = i2 & 2047;              // z 0..1
      transpose64_body(z ? sw2 : sw1, s12t + (size_t)z * CDIM * FSDIM,
                       CDIM, FSDIM, r & 127, r >> 7);
    } else {
      int r = tb - 16384;
      transpose64_body(swp, swpt, FSDIM, CDIM, r & 31, r >> 5);
    }
    return;
  }

  // ---- gate role (bid < 256): scores, top-2 lists, x->bf16 ----
  int gb = bid;
  __shared__ float smat[32][9];   // [token-slot][expert], pad 9
  __shared__ int lcnt[NEXP];
  __shared__ int lbase[NEXP];
  __shared__ int rec_i[32];
  __shared__ int rec_p1[32], rec_p2[32];
  __shared__ float rec_w1[32], rec_w2[32];

  int tid = threadIdx.x, wave = tid >> 6, lane = tid & 63;
  if (tid < NEXP) lcnt[tid] = 0;
  __syncthreads();

  int tbase = gb * 32 + wave * 8;
#pragma unroll
  for (int it = 0; it < 8; ++it) {
    int n = tbase + it;
    const float4* xr = (const float4*)(x + (size_t)n * CDIM) + lane * 4;
    float4 xv[4];
#pragma unroll
    for (int j = 0; j < 4; j++) xv[j] = xr[j];
    u16x8 rA, rB;
    rA[0]=f2bf(xv[0].x); rA[1]=f2bf(xv[0].y); rA[2]=f2bf(xv[0].z); rA[3]=f2bf(xv[0].w);
    rA[4]=f2bf(xv[1].x); rA[5]=f2bf(xv[1].y); rA[6]=f2bf(xv[1].z); rA[7]=f2bf(xv[1].w);
    rB[0]=f2bf(xv[2].x); rB[1]=f2bf(xv[2].y); rB[2]=f2bf(xv[2].z); rB[3]=f2bf(xv[2].w);
    rB[4]=f2bf(xv[3].x); rB[5]=f2bf(xv[3].y); rB[6]=f2bf(xv[3].z); rB[7]=f2bf(xv[3].w);
    u16* xrow = xb + (size_t)n * CDIM + lane * 16;
    *(u16x8*)xrow = rA;
    *(u16x8*)(xrow + 8) = rB;

    float s[NEXP];
#pragma unroll
    for (int e = 0; e < NEXP; e++) {
      const float4* g = (const float4*)(gw + (size_t)e * CDIM) + lane * 4;
      float a = 0.f;
#pragma unroll
      for (int j = 0; j < 4; j++) {
        float4 gv = g[j];
        a += xv[j].x * gv.x + xv[j].y * gv.y + xv[j].z * gv.z + xv[j].w * gv.w;
      }
#pragma unroll
      for (int o = 32; o > 0; o >>= 1) a += __shfl_xor(a, o);
      s[e] = a;
    }
    if (lane == 0) {
      int slot = wave * 8 + it;
#pragma unroll
      for (int e = 0; e < NEXP; e++) {
        scores[(size_t)n * NEXP + e] = s[e];
        smat[slot][e] = s[e];
      }
    }
  }
  __syncthreads();

  // parallel softmax/top-2: one thread per token (32 concurrent)
  if (tid < 32) {
    float p[NEXP];
    float m = smat[tid][0];
#pragma unroll
    for (int e = 1; e < NEXP; e++) m = fmaxf(m, smat[tid][e]);
    float sum = 0.f;
#pragma unroll
    for (int e = 0; e < NEXP; e++) { p[e] = __expf(smat[tid][e] - m); sum += p[e]; }
    int i1 = 0;
#pragma unroll
    for (int e = 1; e < NEXP; e++) if (p[e] > p[i1]) i1 = e;
    int i2 = (i1 == 0) ? 1 : 0;
#pragma unroll
    for (int e = 0; e < NEXP; e++) if (e != i1 && p[e] > p[i2]) i2 = e;
    rec_i[tid] = i1 | (i2 << 8);
    rec_w1[tid] = p[i1] / sum;
    rec_w2[tid] = p[i2] / sum;
    rec_p1[tid] = atomicAdd(&lcnt[i1], 1);
    rec_p2[tid] = atomicAdd(&lcnt[i2], 1);
  }
  __syncthreads();
  if (tid < NEXP) lbase[tid] = atomicAdd(&cnt[tid], lcnt[tid]);
  __syncthreads();
  if (tid < 32) {
    int n = gb * 32 + tid;
    int i1 = rec_i[tid] & 0xff, i2 = rec_i[tid] >> 8;
    int q1 = lbase[i1] + rec_p1[tid];
    int q2 = lbase[i2] + rec_p2[tid];
    tok[i1 * NTOK + q1] = n; wgt[i1 * NTOK + q1] = rec_w1[tid];
    tok[i2 * NTOK + q2] = n; wgt[i2 * NTOK + q2] = rec_w2[tid];
  }
}

#define BM 128
#define BN 128
#define BK 32
#define TILE (BM * BK)   // 4096 u16 = 8 KB

// ---------------- fused SwiGLU GEMM (round-8 loop; m-fastest grid) -----------
// H = silu(A@B1^T) * (A@B2^T); double-buffered LDS, 2-phase, (256,2).
// GRID ORDER: blockIdx.x = m-block (fastest) -> 64 consecutive blocks share
// one 512KB B1+B2 panel (L2-resident per XCD); A streams via L3. Moves 2/3
// of staged loads from L3-latency (~450cy) to L2 (~200cy) in the
// latency-bound 2-phase loop.
// AMODE 0: direct rows; 1: rows gathered via tok list, H written compacted.
template<int AMODE>
__global__ __launch_bounds__(256, 2) void gemm_swiglu(
    const u16* __restrict__ A, int lda,
    const u16* __restrict__ B1, const u16* __restrict__ B2,
    size_t bstride, int ldb,
    int M, int K,
    u16* __restrict__ H, int ldh,
    const int* __restrict__ cnt, const int* __restrict__ tok)
{
  int e = blockIdx.z;
  int Mloc = (AMODE == 0) ? M : cnt[e];
  int mbase = blockIdx.x * BM;     // m fastest-varying
  if (AMODE != 0 && mbase >= Mloc) return;
  int nbase = blockIdx.y * BN;     // weight panel held across 64 consecutive bids
  int tid = threadIdx.x, wid = tid >> 6, lane = tid & 63;

  __shared__ __align__(16) u16 As[2][TILE];
  __shared__ __align__(16) u16 Bs1[2][TILE];
  __shared__ __align__(16) u16 Bs2[2][TILE];

  int sr = lane >> 2;             // 0..15 row within 16-row staging group
  int kg = (lane & 3) * 8;        // 8 bf16 = 16B per lane
  int arow0 = wid * 32 + sr;
  int arow1 = arow0 + 16;

  int pfx = 0;
  if (AMODE != 0) for (int i = 0; i < NEXP; i++) pfx += (i < e) ? cnt[i] : 0;

  size_t r0, r1;
  if (AMODE == 0) {
    r0 = mbase + arow0; r1 = mbase + arow1;
  } else {
    r0 = tok[e * NTOK + min(mbase + arow0, Mloc - 1)];
    r1 = tok[e * NTOK + min(mbase + arow1, Mloc - 1)];
  }
  const u16* Ap0 = A + r0 * (size_t)lda + kg;
  const u16* Ap1 = A + r1 * (size_t)lda + kg;
  size_t boff = (AMODE != 0) ? (size_t)e * bstride : 0;
  const u16* B1p0 = B1 + boff + (size_t)(nbase + arow0) * ldb + kg;
  const u16* B1p1 = B1 + boff + (size_t)(nbase + arow1) * ldb + kg;
  const u16* B2p0 = B2 + boff + (size_t)(nbase + arow0) * ldb + kg;
  const u16* B2p1 = B2 + boff + (size_t)(nbase + arow1) * ldb + kg;

  int ldsw0 = (wid * 32) * BK;        // wave slice, rows [w*32, w*32+16)
  int ldsw1 = (wid * 32 + 16) * BK;   // rows [w*32+16, w*32+32)

  int wr = wid >> 1, wc = wid & 1;
  int fr = lane & 15, fgk = (lane >> 4) * 8;

  f32x4 acc1[4][4] = {};
  f32x4 acc2[4][4] = {};

  int nt = K / BK;
  GLD16(Ap0,  &As [0][ldsw0]); GLD16(Ap1,  &As [0][ldsw1]);
  GLD16(B1p0, &Bs1[0][ldsw0]); GLD16(B1p1, &Bs1[0][ldsw1]);
  GLD16(B2p0, &Bs2[0][ldsw0]); GLD16(B2p1, &Bs2[0][ldsw1]);
  Ap0 += BK; Ap1 += BK; B1p0 += BK; B1p1 += BK; B2p0 += BK; B2p1 += BK;
  __syncthreads();

  int cur = 0;
  for (int t = 0; t < nt; ++t) {
    int nxt = cur ^ 1;
    if (t + 1 < nt) {
      GLD16(Ap0,  &As [nxt][ldsw0]); GLD16(Ap1,  &As [nxt][ldsw1]);
      GLD16(B1p0, &Bs1[nxt][ldsw0]); GLD16(B1p1, &Bs1[nxt][ldsw1]);
      GLD16(B2p0, &Bs2[nxt][ldsw0]); GLD16(B2p1, &Bs2[nxt][ldsw1]);
      Ap0 += BK; Ap1 += BK; B1p0 += BK; B1p1 += BK; B2p0 += BK; B2p1 += BK;
    }
    const u16* as = As[cur];
    const u16* b1s = Bs1[cur];
    const u16* b2s = Bs2[cur];
    bf16x8 af[4], b1f[4], b2f[4];
#pragma unroll
    for (int m = 0; m < 4; m++)
      af[m] = *(const bf16x8*)&as[(wr * 64 + m * 16 + fr) * BK + fgk];
#pragma unroll
    for (int n = 0; n < 4; n++) {
      b1f[n] = *(const bf16x8*)&b1s[(wc * 64 + n * 16 + fr) * BK + fgk];
      b2f[n] = *(const bf16x8*)&b2s[(wc * 64 + n * 16 + fr) * BK + fgk];
    }
#pragma unroll
    for (int m = 0; m < 4; m++)
#pragma unroll
      for (int n = 0; n < 4; n++) {
        acc1[m][n] = __builtin_amdgcn_mfma_f32_16x16x32_bf16(af[m], b1f[n], acc1[m][n], 0, 0, 0);
        acc2[m][n] = __builtin_amdgcn_mfma_f32_16x16x32_bf16(af[m], b2f[n], acc2[m][n], 0, 0, 0);
      }
    __syncthreads();
    cur = nxt;
  }

  int fg4 = (lane >> 4) * 4;
#pragma unroll
  for (int m = 0; m < 4; m++) {
#pragma unroll
    for (int j = 0; j < 4; j++) {
      int rloc = wr * 64 + m * 16 + fg4 + j;
      int rr = mbase + rloc;
      if (AMODE != 0 && rr >= Mloc) continue;
      size_t orow = (size_t)(pfx + rr);
#pragma unroll
      for (int n = 0; n < 4; n++) {
        int col = nbase + wc * 64 + n * 16 + fr;
        float g = acc1[m][n][j];
        float v = acc2[m][n][j];
        float hv = (g / (1.f + __expf(-g))) * v;   // silu(g)*v
        H[orow * (size_t)ldh + col] = f2bf(hv);
      }
    }
  }
}

// ---------------- proj GEMM: (256,3), m-fastest grid ------------------------
// EPI: 2 store f32, 4 *wgt + atomicAdd scatter to out rows tok[].
// AMODE: 0 direct rows, 2 rows at prefix[e]+r (compacted expert h).
template<int EPI, int AMODE>
__global__ __launch_bounds__(256, 3) void gemm_proj(
    const u16* __restrict__ A, int lda,
    const u16* __restrict__ B, size_t bstride, int ldb,
    int M, int K,
    float* __restrict__ outF, int ldo,
    const int* __restrict__ cnt, const int* __restrict__ tok,
    const float* __restrict__ wgt)
{
  int e = blockIdx.z;
  int Mloc = (AMODE == 0) ? M : cnt[e];
  int mbase = blockIdx.x * BM;     // m fastest-varying
  if (AMODE != 0 && mbase >= Mloc) return;
  int nbase = blockIdx.y * BN;
  int tid = threadIdx.x, wid = tid >> 6, lane = tid & 63;

  __shared__ __align__(16) u16 As[2][TILE];
  __shared__ __align__(16) u16 Bs[2][TILE];

  int sr = lane >> 2;
  int kg = (lane & 3) * 8;
  int arow0 = wid * 32 + sr;
  int arow1 = arow0 + 16;

  int pfx = 0;
  if (AMODE != 0) for (int i = 0; i < NEXP; i++) pfx += (i < e) ? cnt[i] : 0;

  size_t r0, r1;
  if (AMODE == 0) {
    r0 = mbase + arow0; r1 = mbase + arow1;
  } else {
    r0 = pfx + min(mbase + arow0, Mloc - 1);
    r1 = pfx + min(mbase + arow1, Mloc - 1);
  }
  const u16* Ap0 = A + r0 * (size_t)lda + kg;
  const u16* Ap1 = A + r1 * (size_t)lda + kg;
  const u16* Bb = B + ((AMODE != 0) ? (size_t)e * bstride : 0);
  const u16* Bp0 = Bb + (size_t)(nbase + arow0) * ldb + kg;
  const u16* Bp1 = Bb + (size_t)(nbase + arow1) * ldb + kg;

  int ldsw0 = (wid * 32) * BK;
  int ldsw1 = (wid * 32 + 16) * BK;

  int wr = wid >> 1, wc = wid & 1;
  int fr = lane & 15, fgk = (lane >> 4) * 8;

  f32x4 acc[4][4] = {};

  int nt = K / BK;
  GLD16(Ap0, &As[0][ldsw0]); GLD16(Ap1, &As[0][ldsw1]);
  GLD16(Bp0, &Bs[0][ldsw0]); GLD16(Bp1, &Bs[0][ldsw1]);
  Ap0 += BK; Ap1 += BK; Bp0 += BK; Bp1 += BK;
  __syncthreads();

  int cur = 0;
  for (int t = 0; t < nt; ++t) {
    int nxt = cur ^ 1;
    if (t + 1 < nt) {
      GLD16(Ap0, &As[nxt][ldsw0]); GLD16(Ap1, &As[nxt][ldsw1]);
      GLD16(Bp0, &Bs[nxt][ldsw0]); GLD16(Bp1, &Bs[nxt][ldsw1]);
      Ap0 += BK; Ap1 += BK; Bp0 += BK; Bp1 += BK;
    }
    const u16* as = As[cur];
    const u16* bs = Bs[cur];
    bf16x8 af[4], bfr[4];
#pragma unroll
    for (int m = 0; m < 4; m++)
      af[m] = *(const bf16x8*)&as[(wr * 64 + m * 16 + fr) * BK + fgk];
#pragma unroll
    for (int n = 0; n < 4; n++)
      bfr[n] = *(const bf16x8*)&bs[(wc * 64 + n * 16 + fr) * BK + fgk];
#pragma unroll
    for (int m = 0; m < 4; m++)
#pragma unroll
      for (int n = 0; n < 4; n++)
        acc[m][n] = __builtin_amdgcn_mfma_f32_16x16x32_bf16(af[m], bfr[n], acc[m][n], 0, 0, 0);
    __syncthreads();
    cur = nxt;
  }

  int fg4 = (lane >> 4) * 4;
#pragma unroll
  for (int m = 0; m < 4; m++) {
#pragma unroll
    for (int j = 0; j < 4; j++) {
      int rloc = wr * 64 + m * 16 + fg4 + j;
      int rr = mbase + rloc;
      if (AMODE != 0 && rr >= Mloc) continue;
      int t = 0; float wv = 0.f;
      if (EPI == 4) { t = tok[e * NTOK + rr]; wv = wgt[e * NTOK + rr]; }
#pragma unroll
      for (int n = 0; n < 4; n++) {
        int col = nbase + wc * 64 + n * 16 + fr;
        float v = acc[m][n][j];
        if (EPI == 2) {
          outF[(size_t)rr * ldo + col] = v;
        } else {
          unsafeAtomicAdd(&outF[(size_t)t * ldo + col], v * wv);
        }
      }
    }
  }
}

// ---------------- host ----------------
extern "C" void kernel_launch(void* const* d_in, const int* in_sizes, int n_in,
                              void* d_out, int out_size, void* d_ws, size_t ws_size,
                              hipStream_t stream)
{
  const float* x   = (const float*)d_in[0];
  const float* gw  = (const float*)d_in[1];
  const float* ew1 = (const float*)d_in[2];
  const float* ew2 = (const float*)d_in[3];
  const float* ewp = (const float*)d_in[4];
  const float* sw1 = (const float*)d_in[5];
  const float* sw2 = (const float*)d_in[6];
  const float* swp = (const float*)d_in[7];
  float* out    = (float*)d_out;
  float* scores = out + (size_t)NTOK * CDIM;

  char* wsp = (char*)d_ws;
  size_t off = 0;
  auto alloc = [&](size_t bytes) -> void* {
    void* p = wsp + off; off += (bytes + 255) & ~(size_t)255; return p;
  };
  u16* xb   = (u16*)alloc((size_t)NTOK * CDIM * 2);
  u16* eall = (u16*)alloc((size_t)24 * CDIM * FEDIM * 2);   // [ew1t|ew2t|ewpt]
  u16* ew1t = eall;
  u16* ew2t = eall + (size_t)8 * CDIM * FEDIM;
  u16* ewpt = eall + (size_t)16 * CDIM * FEDIM;
  u16* s12t = (u16*)alloc((size_t)2 * FSDIM * CDIM * 2);    // [sw1t|sw2t]
  u16* sw1t = s12t;
  u16* sw2t = s12t + (size_t)FSDIM * CDIM;
  u16* swpt = (u16*)alloc((size_t)CDIM * FSDIM * 2);
  u16* hs   = (u16*)alloc((size_t)NTOK * FSDIM * 2);   // shared h (64 MB)
  u16* he   = hs;   // expert h (32 MB) ALIASES hs: hs dead before he written
  int* cnt  = (int*)alloc(256);
  int* tok  = (int*)alloc((size_t)NEXP * NTOK * 4);
  float* wgt = (float*)alloc((size_t)NEXP * NTOK * 4);
  if (off > ws_size) return;

  hipMemsetAsync(cnt, 0, 32, stream);

  // ONE prep launch: gate (bid<256, leads dispatch) + all weight transposes
  prep_kernel<<<18688, 256, 0, stream>>>(x, gw, ew1, ew2, ewp, sw1, sw2, swp,
                                         scores, xb, cnt, tok, wgt,
                                         eall, s12t, swpt);

  // shared FFN (grids now m-fastest: dim3(M-blocks, N-blocks, z))
  gemm_swiglu<0><<<dim3(NTOK/BM, FSDIM/BN, 1), 256, 0, stream>>>(
      xb, CDIM, sw1t, sw2t, 0, CDIM, NTOK, CDIM, hs, FSDIM, nullptr, nullptr);
  gemm_proj<2,0><<<dim3(NTOK/BM, CDIM/BN, 1), 256, 0, stream>>>(
      hs, FSDIM, swpt, 0, FSDIM, NTOK, FSDIM, out, CDIM, nullptr, nullptr, nullptr);

  // experts: fused SwiGLU on gathered rows, then proj with weighted scatter
  size_t estride = (size_t)FEDIM * CDIM;
  gemm_swiglu<1><<<dim3(NTOK/BM, FEDIM/BN, NEXP), 256, 0, stream>>>(
      xb, CDIM, ew1t, ew2t, estride, CDIM, 0, CDIM, he, FEDIM, cnt, tok);
  gemm_proj<4,2><<<dim3(NTOK/BM, CDIM/BN, NEXP), 256, 0, stream>>>(
      he, FEDIM, ewpt, estride, FEDIM, 0, FEDIM, out, CDIM, cnt, tok, wgt);
}

// Round 17
// 556.700 us; speedup vs baseline: 1.0682x; 1.0682x over previous
//
#include <hip/hip_runtime.h>

typedef unsigned short u16;
typedef unsigned int u32;
typedef __bf16 bf16x8 __attribute__((ext_vector_type(8)));
typedef float f32x4 __attribute__((ext_vector_type(4)));
typedef u16 u16x8 __attribute__((ext_vector_type(8)));

#define NTOK 8192
#define CDIM 1024
#define NEXP 8
#define FEDIM 1024
#define FSDIM 4096

#define GLD16(gp, lp) __builtin_amdgcn_global_load_lds( \
    (const __attribute__((address_space(1))) void*)(gp), \
    (__attribute__((address_space(3))) void*)(lp), 16, 0, 0)

__device__ __forceinline__ u16 f2bf(float f) {
  u32 u = __float_as_uint(f);
  u += 0x7FFFu + ((u >> 16) & 1u);   // RNE
  return (u16)(u >> 16);
}

// ---- 64x32 transpose tile body: src f32[R][C] -> dst bf16[C][R] ------------
__device__ __forceinline__ void transpose64_body(
    const float* __restrict__ src, u16* __restrict__ dst,
    int R, int C, int bx, int by)
{
  __shared__ float tile[64][33];
  int c0 = bx * 32, r0 = by * 64;
  int tx = threadIdx.x & 31, ty = threadIdx.x >> 5;   // ty 0..7
#pragma unroll
  for (int p = 0; p < 8; p++) {
    int r = ty + p * 8;
    tile[r][tx] = src[(size_t)(r0 + r) * C + c0 + tx];
  }
  __syncthreads();
#pragma unroll
  for (int p = 0; p < 4; p++) {
    int cc = ty + p * 8;
    u32 v = (u32)f2bf(tile[2 * tx][cc]) | ((u32)f2bf(tile[2 * tx + 1][cc]) << 16);
    *(u32*)&dst[(size_t)(c0 + cc) * R + r0 + 2 * tx] = v;
  }
}

// ---------------- prep: gate FIRST, then all transposes, ONE launch ----------
// flat bid roles: [0,256) gate; [256,12544) expert-trio transpose
// (24 x 1024^2); [12544,16640) shared W1/W2 pair; [16640,18688) swp.
__global__ __launch_bounds__(256) void prep_kernel(
    const float* __restrict__ x, const float* __restrict__ gw,
    const float* __restrict__ ew1, const float* __restrict__ ew2,
    const float* __restrict__ ewp, const float* __restrict__ sw1,
    const float* __restrict__ sw2, const float* __restrict__ swp,
    float* __restrict__ scores, u16* __restrict__ xb, int* __restrict__ cnt,
    int* __restrict__ tok, float* __restrict__ wgt,
    u16* __restrict__ eall, u16* __restrict__ s12t, u16* __restrict__ swpt)
{
  int bid = blockIdx.x;
  if (bid >= 256) {
    int tb = bid - 256;
    if (tb < 12288) {
      int z = tb >> 9, r = tb & 511;                // z 0..23
      const float* src = (z < 8) ? ew1 : ((z < 16) ? ew2 : ewp);
      transpose64_body(src + (size_t)(z & 7) * CDIM * FEDIM,
                       eall + (size_t)z * CDIM * FEDIM,
                       CDIM, FEDIM, r & 31, r >> 5);
    } else if (tb < 16384) {
      int i2 = tb - 12288;
      int z = i2 >> 11, r = i2 & 2047;              // z 0..1
      transpose64_body(z ? sw2 : sw1, s12t + (size_t)z * CDIM * FSDIM,
                       CDIM, FSDIM, r & 127, r >> 7);
    } else {
      int r = tb - 16384;
      transpose64_body(swp, swpt, FSDIM, CDIM, r & 31, r >> 5);
    }
    return;
  }

  // ---- gate role (bid < 256): scores, top-2 lists, x->bf16 ----
  int gb = bid;
  __shared__ float smat[32][9];   // [token-slot][expert], pad 9
  __shared__ int lcnt[NEXP];
  __shared__ int lbase[NEXP];
  __shared__ int rec_i[32];
  __shared__ int rec_p1[32], rec_p2[32];
  __shared__ float rec_w1[32], rec_w2[32];

  int tid = threadIdx.x, wave = tid >> 6, lane = tid & 63;
  if (tid < NEXP) lcnt[tid] = 0;
  __syncthreads();

  int tbase = gb * 32 + wave * 8;
#pragma unroll
  for (int it = 0; it < 8; ++it) {
    int n = tbase + it;
    const float4* xr = (const float4*)(x + (size_t)n * CDIM) + lane * 4;
    float4 xv[4];
#pragma unroll
    for (int j = 0; j < 4; j++) xv[j] = xr[j];
    u16x8 rA, rB;
    rA[0]=f2bf(xv[0].x); rA[1]=f2bf(xv[0].y); rA[2]=f2bf(xv[0].z); rA[3]=f2bf(xv[0].w);
    rA[4]=f2bf(xv[1].x); rA[5]=f2bf(xv[1].y); rA[6]=f2bf(xv[1].z); rA[7]=f2bf(xv[1].w);
    rB[0]=f2bf(xv[2].x); rB[1]=f2bf(xv[2].y); rB[2]=f2bf(xv[2].z); rB[3]=f2bf(xv[2].w);
    rB[4]=f2bf(xv[3].x); rB[5]=f2bf(xv[3].y); rB[6]=f2bf(xv[3].z); rB[7]=f2bf(xv[3].w);
    u16* xrow = xb + (size_t)n * CDIM + lane * 16;
    *(u16x8*)xrow = rA;
    *(u16x8*)(xrow + 8) = rB;

    float s[NEXP];
#pragma unroll
    for (int e = 0; e < NEXP; e++) {
      const float4* g = (const float4*)(gw + (size_t)e * CDIM) + lane * 4;
      float a = 0.f;
#pragma unroll
      for (int j = 0; j < 4; j++) {
        float4 gv = g[j];
        a += xv[j].x * gv.x + xv[j].y * gv.y + xv[j].z * gv.z + xv[j].w * gv.w;
      }
#pragma unroll
      for (int o = 32; o > 0; o >>= 1) a += __shfl_xor(a, o);
      s[e] = a;
    }
    if (lane == 0) {
      int slot = wave * 8 + it;
#pragma unroll
      for (int e = 0; e < NEXP; e++) {
        scores[(size_t)n * NEXP + e] = s[e];
        smat[slot][e] = s[e];
      }
    }
  }
  __syncthreads();

  // parallel softmax/top-2: one thread per token (32 concurrent)
  if (tid < 32) {
    float p[NEXP];
    float m = smat[tid][0];
#pragma unroll
    for (int e = 1; e < NEXP; e++) m = fmaxf(m, smat[tid][e]);
    float sum = 0.f;
#pragma unroll
    for (int e = 0; e < NEXP; e++) { p[e] = __expf(smat[tid][e] - m); sum += p[e]; }
    int i1 = 0;
#pragma unroll
    for (int e = 1; e < NEXP; e++) if (p[e] > p[i1]) i1 = e;
    int i2 = (i1 == 0) ? 1 : 0;
#pragma unroll
    for (int e = 0; e < NEXP; e++) if (e != i1 && p[e] > p[i2]) i2 = e;
    rec_i[tid] = i1 | (i2 << 8);
    rec_w1[tid] = p[i1] / sum;
    rec_w2[tid] = p[i2] / sum;
    rec_p1[tid] = atomicAdd(&lcnt[i1], 1);
    rec_p2[tid] = atomicAdd(&lcnt[i2], 1);
  }
  __syncthreads();
  if (tid < NEXP) lbase[tid] = atomicAdd(&cnt[tid], lcnt[tid]);
  __syncthreads();
  if (tid < 32) {
    int n = gb * 32 + tid;
    int i1 = rec_i[tid] & 0xff, i2 = rec_i[tid] >> 8;
    int q1 = lbase[i1] + rec_p1[tid];
    int q2 = lbase[i2] + rec_p2[tid];
    tok[i1 * NTOK + q1] = n; wgt[i1 * NTOK + q1] = rec_w1[tid];
    tok[i2 * NTOK + q2] = n; wgt[i2 * NTOK + q2] = rec_w2[tid];
  }
}

#define BM 128
#define BN 128
#define BK 32
#define TILE (BM * BK)   // 4096 u16 = 8 KB

// ---------------- fused SwiGLU GEMM (round-8 verbatim, 808 TF) ---------------
// H = silu(A@B1^T) * (A@B2^T); double-buffered LDS, 2-phase, (256,2).
// Dual accumulator = 32 MFMA per staged A-tile (2x arithmetic intensity).
// n-fastest grid (round 16 proved m-fastest regresses).
// AMODE 0: direct rows; 1: rows gathered via tok list, H written compacted.
template<int AMODE>
__global__ __launch_bounds__(256, 2) void gemm_swiglu(
    const u16* __restrict__ A, int lda,
    const u16* __restrict__ B1, const u16* __restrict__ B2,
    size_t bstride, int ldb,
    int M, int K,
    u16* __restrict__ H, int ldh,
    const int* __restrict__ cnt, const int* __restrict__ tok)
{
  int e = blockIdx.z;
  int Mloc = (AMODE == 0) ? M : cnt[e];
  int mbase = blockIdx.y * BM;
  if (AMODE != 0 && mbase >= Mloc) return;
  int nbase = blockIdx.x * BN;
  int tid = threadIdx.x, wid = tid >> 6, lane = tid & 63;

  __shared__ __align__(16) u16 As[2][TILE];
  __shared__ __align__(16) u16 Bs1[2][TILE];
  __shared__ __align__(16) u16 Bs2[2][TILE];

  int sr = lane >> 2;             // 0..15 row within 16-row staging group
  int kg = (lane & 3) * 8;        // 8 bf16 = 16B per lane
  int arow0 = wid * 32 + sr;
  int arow1 = arow0 + 16;

  int pfx = 0;
  if (AMODE != 0) for (int i = 0; i < NEXP; i++) pfx += (i < e) ? cnt[i] : 0;

  size_t r0, r1;
  if (AMODE == 0) {
    r0 = mbase + arow0; r1 = mbase + arow1;
  } else {
    r0 = tok[e * NTOK + min(mbase + arow0, Mloc - 1)];
    r1 = tok[e * NTOK + min(mbase + arow1, Mloc - 1)];
  }
  const u16* Ap0 = A + r0 * (size_t)lda + kg;
  const u16* Ap1 = A + r1 * (size_t)lda + kg;
  size_t boff = (AMODE != 0) ? (size_t)e * bstride : 0;
  const u16* B1p0 = B1 + boff + (size_t)(nbase + arow0) * ldb + kg;
  const u16* B1p1 = B1 + boff + (size_t)(nbase + arow1) * ldb + kg;
  const u16* B2p0 = B2 + boff + (size_t)(nbase + arow0) * ldb + kg;
  const u16* B2p1 = B2 + boff + (size_t)(nbase + arow1) * ldb + kg;

  int ldsw0 = (wid * 32) * BK;        // wave slice, rows [w*32, w*32+16)
  int ldsw1 = (wid * 32 + 16) * BK;   // rows [w*32+16, w*32+32)

  int wr = wid >> 1, wc = wid & 1;
  int fr = lane & 15, fgk = (lane >> 4) * 8;

  f32x4 acc1[4][4] = {};
  f32x4 acc2[4][4] = {};

  int nt = K / BK;
  GLD16(Ap0,  &As [0][ldsw0]); GLD16(Ap1,  &As [0][ldsw1]);
  GLD16(B1p0, &Bs1[0][ldsw0]); GLD16(B1p1, &Bs1[0][ldsw1]);
  GLD16(B2p0, &Bs2[0][ldsw0]); GLD16(B2p1, &Bs2[0][ldsw1]);
  Ap0 += BK; Ap1 += BK; B1p0 += BK; B1p1 += BK; B2p0 += BK; B2p1 += BK;
  __syncthreads();

  int cur = 0;
  for (int t = 0; t < nt; ++t) {
    int nxt = cur ^ 1;
    if (t + 1 < nt) {
      GLD16(Ap0,  &As [nxt][ldsw0]); GLD16(Ap1,  &As [nxt][ldsw1]);
      GLD16(B1p0, &Bs1[nxt][ldsw0]); GLD16(B1p1, &Bs1[nxt][ldsw1]);
      GLD16(B2p0, &Bs2[nxt][ldsw0]); GLD16(B2p1, &Bs2[nxt][ldsw1]);
      Ap0 += BK; Ap1 += BK; B1p0 += BK; B1p1 += BK; B2p0 += BK; B2p1 += BK;
    }
    const u16* as = As[cur];
    const u16* b1s = Bs1[cur];
    const u16* b2s = Bs2[cur];
    bf16x8 af[4], b1f[4], b2f[4];
#pragma unroll
    for (int m = 0; m < 4; m++)
      af[m] = *(const bf16x8*)&as[(wr * 64 + m * 16 + fr) * BK + fgk];
#pragma unroll
    for (int n = 0; n < 4; n++) {
      b1f[n] = *(const bf16x8*)&b1s[(wc * 64 + n * 16 + fr) * BK + fgk];
      b2f[n] = *(const bf16x8*)&b2s[(wc * 64 + n * 16 + fr) * BK + fgk];
    }
#pragma unroll
    for (int m = 0; m < 4; m++)
#pragma unroll
      for (int n = 0; n < 4; n++) {
        acc1[m][n] = __builtin_amdgcn_mfma_f32_16x16x32_bf16(af[m], b1f[n], acc1[m][n], 0, 0, 0);
        acc2[m][n] = __builtin_amdgcn_mfma_f32_16x16x32_bf16(af[m], b2f[n], acc2[m][n], 0, 0, 0);
      }
    __syncthreads();
    cur = nxt;
  }

  int fg4 = (lane >> 4) * 4;
#pragma unroll
  for (int m = 0; m < 4; m++) {
#pragma unroll
    for (int j = 0; j < 4; j++) {
      int rloc = wr * 64 + m * 16 + fg4 + j;
      int rr = mbase + rloc;
      if (AMODE != 0 && rr >= Mloc) continue;
      size_t orow = (size_t)(pfx + rr);
#pragma unroll
      for (int n = 0; n < 4; n++) {
        int col = nbase + wc * 64 + n * 16 + fr;
        float g = acc1[m][n][j];
        float v = acc2[m][n][j];
        float hv = (g / (1.f + __expf(-g))) * v;   // silu(g)*v
        H[orow * (size_t)ldh + col] = f2bf(hv);
      }
    }
  }
}

// ---------------- proj GEMM: (256,3) — 3 blocks/CU ---------------------------
// EPI: 2 store f32, 4 *wgt + atomicAdd scatter to out rows tok[].
// AMODE: 0 direct rows, 2 rows at prefix[e]+r (compacted expert h).
template<int EPI, int AMODE>
__global__ __launch_bounds__(256, 3) void gemm_proj(
    const u16* __restrict__ A, int lda,
    const u16* __restrict__ B, size_t bstride, int ldb,
    int M, int K,
    float* __restrict__ outF, int ldo,
    const int* __restrict__ cnt, const int* __restrict__ tok,
    const float* __restrict__ wgt)
{
  int e = blockIdx.z;
  int Mloc = (AMODE == 0) ? M : cnt[e];
  int mbase = blockIdx.y * BM;
  if (AMODE != 0 && mbase >= Mloc) return;
  int nbase = blockIdx.x * BN;
  int tid = threadIdx.x, wid = tid >> 6, lane = tid & 63;

  __shared__ __align__(16) u16 As[2][TILE];
  __shared__ __align__(16) u16 Bs[2][TILE];

  int sr = lane >> 2;
  int kg = (lane & 3) * 8;
  int arow0 = wid * 32 + sr;
  int arow1 = arow0 + 16;

  int pfx = 0;
  if (AMODE != 0) for (int i = 0; i < NEXP; i++) pfx += (i < e) ? cnt[i] : 0;

  size_t r0, r1;
  if (AMODE == 0) {
    r0 = mbase + arow0; r1 = mbase + arow1;
  } else {
    r0 = pfx + min(mbase + arow0, Mloc - 1);
    r1 = pfx + min(mbase + arow1, Mloc - 1);
  }
  const u16* Ap0 = A + r0 * (size_t)lda + kg;
  const u16* Ap1 = A + r1 * (size_t)lda + kg;
  const u16* Bb = B + ((AMODE != 0) ? (size_t)e * bstride : 0);
  const u16* Bp0 = Bb + (size_t)(nbase + arow0) * ldb + kg;
  const u16* Bp1 = Bb + (size_t)(nbase + arow1) * ldb + kg;

  int ldsw0 = (wid * 32) * BK;
  int ldsw1 = (wid * 32 + 16) * BK;

  int wr = wid >> 1, wc = wid & 1;
  int fr = lane & 15, fgk = (lane >> 4) * 8;

  f32x4 acc[4][4] = {};

  int nt = K / BK;
  GLD16(Ap0, &As[0][ldsw0]); GLD16(Ap1, &As[0][ldsw1]);
  GLD16(Bp0, &Bs[0][ldsw0]); GLD16(Bp1, &Bs[0][ldsw1]);
  Ap0 += BK; Ap1 += BK; Bp0 += BK; Bp1 += BK;
  __syncthreads();

  int cur = 0;
  for (int t = 0; t < nt; ++t) {
    int nxt = cur ^ 1;
    if (t + 1 < nt) {
      GLD16(Ap0, &As[nxt][ldsw0]); GLD16(Ap1, &As[nxt][ldsw1]);
      GLD16(Bp0, &Bs[nxt][ldsw0]); GLD16(Bp1, &Bs[nxt][ldsw1]);
      Ap0 += BK; Ap1 += BK; Bp0 += BK; Bp1 += BK;
    }
    const u16* as = As[cur];
    const u16* bs = Bs[cur];
    bf16x8 af[4], bfr[4];
#pragma unroll
    for (int m = 0; m < 4; m++)
      af[m] = *(const bf16x8*)&as[(wr * 64 + m * 16 + fr) * BK + fgk];
#pragma unroll
    for (int n = 0; n < 4; n++)
      bfr[n] = *(const bf16x8*)&bs[(wc * 64 + n * 16 + fr) * BK + fgk];
#pragma unroll
    for (int m = 0; m < 4; m++)
#pragma unroll
      for (int n = 0; n < 4; n++)
        acc[m][n] = __builtin_amdgcn_mfma_f32_16x16x32_bf16(af[m], bfr[n], acc[m][n], 0, 0, 0);
    __syncthreads();
    cur = nxt;
  }

  int fg4 = (lane >> 4) * 4;
#pragma unroll
  for (int m = 0; m < 4; m++) {
#pragma unroll
    for (int j = 0; j < 4; j++) {
      int rloc = wr * 64 + m * 16 + fg4 + j;
      int rr = mbase + rloc;
      if (AMODE != 0 && rr >= Mloc) continue;
      int t = 0; float wv = 0.f;
      if (EPI == 4) { t = tok[e * NTOK + rr]; wv = wgt[e * NTOK + rr]; }
#pragma unroll
      for (int n = 0; n < 4; n++) {
        int col = nbase + wc * 64 + n * 16 + fr;
        float v = acc[m][n][j];
        if (EPI == 2) {
          outF[(size_t)rr * ldo + col] = v;
        } else {
          unsafeAtomicAdd(&outF[(size_t)t * ldo + col], v * wv);
        }
      }
    }
  }
}

// ---------------- host ----------------
extern "C" void kernel_launch(void* const* d_in, const int* in_sizes, int n_in,
                              void* d_out, int out_size, void* d_ws, size_t ws_size,
                              hipStream_t stream)
{
  const float* x   = (const float*)d_in[0];
  const float* gw  = (const float*)d_in[1];
  const float* ew1 = (const float*)d_in[2];
  const float* ew2 = (const float*)d_in[3];
  const float* ewp = (const float*)d_in[4];
  const float* sw1 = (const float*)d_in[5];
  const float* sw2 = (const float*)d_in[6];
  const float* swp = (const float*)d_in[7];
  float* out    = (float*)d_out;
  float* scores = out + (size_t)NTOK * CDIM;

  char* wsp = (char*)d_ws;
  size_t off = 0;
  auto alloc = [&](size_t bytes) -> void* {
    void* p = wsp + off; off += (bytes + 255) & ~(size_t)255; return p;
  };
  u16* xb   = (u16*)alloc((size_t)NTOK * CDIM * 2);
  u16* eall = (u16*)alloc((size_t)24 * CDIM * FEDIM * 2);   // [ew1t|ew2t|ewpt]
  u16* ew1t = eall;
  u16* ew2t = eall + (size_t)8 * CDIM * FEDIM;
  u16* ewpt = eall + (size_t)16 * CDIM * FEDIM;
  u16* s12t = (u16*)alloc((size_t)2 * FSDIM * CDIM * 2);    // [sw1t|sw2t]
  u16* sw1t = s12t;
  u16* sw2t = s12t + (size_t)FSDIM * CDIM;
  u16* swpt = (u16*)alloc((size_t)CDIM * FSDIM * 2);
  u16* hs   = (u16*)alloc((size_t)NTOK * FSDIM * 2);   // shared h (64 MB)
  u16* he   = hs;   // expert h (32 MB) ALIASES hs: hs dead before he written
  int* cnt  = (int*)alloc(256);
  int* tok  = (int*)alloc((size_t)NEXP * NTOK * 4);
  float* wgt = (float*)alloc((size_t)NEXP * NTOK * 4);
  if (off > ws_size) return;

  hipMemsetAsync(cnt, 0, 32, stream);

  // ONE prep launch: gate (bid<256, leads dispatch) + all weight transposes
  prep_kernel<<<18688, 256, 0, stream>>>(x, gw, ew1, ew2, ewp, sw1, sw2, swp,
                                         scores, xb, cnt, tok, wgt,
                                         eall, s12t, swpt);

  // shared FFN: fused SwiGLU (N=4096, K=1024) then proj (N=1024, K=4096)
  gemm_swiglu<0><<<dim3(FSDIM/BN, NTOK/BM, 1), 256, 0, stream>>>(
      xb, CDIM, sw1t, sw2t, 0, CDIM, NTOK, CDIM, hs, FSDIM, nullptr, nullptr);
  gemm_proj<2,0><<<dim3(CDIM/BN, NTOK/BM, 1), 256, 0, stream>>>(
      hs, FSDIM, swpt, 0, FSDIM, NTOK, FSDIM, out, CDIM, nullptr, nullptr, nullptr);

  // experts: fused SwiGLU on gathered rows, then proj with weighted scatter
  size_t estride = (size_t)FEDIM * CDIM;
  gemm_swiglu<1><<<dim3(FEDIM/BN, NTOK/BM, NEXP), 256, 0, stream>>>(
      xb, CDIM, ew1t, ew2t, estride, CDIM, 0, CDIM, he, FEDIM, cnt, tok);
  gemm_proj<4,2><<<dim3(CDIM/BN, NTOK/BM, NEXP), 256, 0, stream>>>(
      he, FEDIM, ewpt, estride, FEDIM, 0, FEDIM, out, CDIM, cnt, tok, wgt);
}